// Round 8
// baseline (361.768 us; speedup 1.0000x reference)
//
#include <hip/hip_runtime.h>
#include <hip/hip_bf16.h>

typedef unsigned short ushort_t;
typedef __attribute__((ext_vector_type(8))) short bf16x8;   // 8 bf16 = 4 VGPRs
typedef __attribute__((ext_vector_type(4))) float f32x4;    // 4 fp32 acc

#define MDIM 2048
#define NDIM 4096

__device__ __forceinline__ ushort_t to_bf16(float f) {
    __hip_bfloat16 h = __float2bfloat16(f);
    return *reinterpret_cast<ushort_t*>(&h);
}

// ---------------- prep: fp32 -> bf16 cast ----------------
__global__ void cast_bf16_kernel(const float* __restrict__ in, ushort_t* __restrict__ out, int n) {
    int i = blockIdx.x * blockDim.x + threadIdx.x;
    if (i < n) out[i] = to_bf16(in[i]);
}

// ---------------- prep: W[K][N] fp32 -> WT[N][K] bf16 ----------------
__global__ void transpose_cast_kernel(const float* __restrict__ W, ushort_t* __restrict__ WT,
                                      int K, int N) {
    __shared__ float tile[32][33];
    const int tx = threadIdx.x, ty = threadIdx.y;  // (32, 8)
    const int n0 = blockIdx.x * 32, k0 = blockIdx.y * 32;
#pragma unroll
    for (int r = 0; r < 4; ++r)
        tile[ty + r * 8][tx] = W[(size_t)(k0 + ty + r * 8) * N + n0 + tx];
    __syncthreads();
    const int t = ty * 32 + tx;
    const int nl = t >> 3;          // 0..31 : local n
    const int kc = (t & 7) * 4;     // 0..28 : k chunk of 4
    ushort4 o;
    o.x = to_bf16(tile[kc + 0][nl]);
    o.y = to_bf16(tile[kc + 1][nl]);
    o.z = to_bf16(tile[kc + 2][nl]);
    o.w = to_bf16(tile[kc + 3][nl]);
    *reinterpret_cast<ushort4*>(&WT[(size_t)(n0 + nl) * K + k0 + kc]) = o;
}

// ---------------- GEMM v9: 4 waves x 64x128 tiles (port-traffic cut) ----------------
// C[M][N] = act(A[M][K] @ BT[N][K]^T + bias)
// BM=128, BN=256, BK=64, 4 waves (2Mx2N), wave tile 64x128. Grid 16x16 = 1/CU.
// v8 post-mortem: lgkm-split neutral - the compiler already emits counted
// lgkmcnt (m97). The binding resource is the LDS PORT, serving reads AND the
// global_load_lds writes: 128 b128 reads (1536cyc) + 48KB GLD writes (~576cyc)
// = 2112cyc/tile saturated, + ~620 MFMA tail = 2730 ~= measured 2775. MFMA
// demand (1240/SIMD) is BELOW port demand -> cut port traffic, not schedule.
// Reads deliver 128KB/tile for 48KB unique (A dup x4, B x2) under the 2Mx4N
// wave grid. v9: 4 waves, 64x128 tiles (2Mx2N) -> dup x2/x2, reads 96 (1152cyc),
// port 1728, MFMA/SIMD 1242 (1 wave/SIMD, 64 MFMA) -> tile ~2100-2350cyc.
// Staging/swizzle/vmcnt structure unchanged (12 GLDs/wave/tile -> vmcnt(12));
// per-acc MFMA order unchanged (kk0,kk1; i-major,j-minor) -> bitwise-identical.

#define GLD(gp, lp) __builtin_amdgcn_global_load_lds(                      \
        (const __attribute__((address_space(1))) void*)(gp),               \
        (__attribute__((address_space(3))) void*)(lp), 16, 0, 0)

#define MFMA(d, a, b) d = __builtin_amdgcn_mfma_f32_16x16x32_bf16(a, b, d, 0, 0, 0)

template <typename OutT, bool RELU>
__global__ __launch_bounds__(256, 1) void gemm_p8(const ushort_t* __restrict__ A,
                                                  const ushort_t* __restrict__ BT,
                                                  const float* __restrict__ bias,
                                                  OutT* __restrict__ C, int Kdim) {
    __shared__ __align__(16) ushort_t As[3][128 * 64];   // 48 KB
    __shared__ __align__(16) ushort_t Bs[3][256 * 64];   // 96 KB

    const int t = threadIdx.x;
    const int l = t & 63;
    const int w = t >> 6;          // wave 0..3
    const int l16 = l & 15;
    const int quad = l >> 4;
    const int wr = w >> 1;         // 0..1  (M): 64-row slab
    const int wc = w & 1;          // 0..1  (N): 128-col slab
    const int m0 = blockIdx.y * 128;
    const int n0 = blockIdx.x * 256;

    f32x4 acc[4][8];
#pragma unroll
    for (int i = 0; i < 4; ++i)
#pragma unroll
        for (int j = 0; j < 8; ++j) acc[i][j] = (f32x4){0.f, 0.f, 0.f, 0.f};

    // --- staging addressing (chunk-XOR swizzle, verified conflict-free) ---
    // 4 waves x 12 GLD: each GLD covers 32 rows (wave w rows w*8..w*8+8 of each
    // 32-row group; lane l -> row +(l>>3), LDS chunk l&7 linear; global source
    // chunk inverse-swizzled).
    const int srow = w * 8 + (l >> 3);            // 0..31
    const int scol = ((l & 7) ^ (l >> 3)) * 8;    // swizzled 16B chunk in K-tile
    const ushort_t* gA = A  + (size_t)(m0 + srow) * Kdim + scol;
    const ushort_t* gB = BT + (size_t)(n0 + srow) * Kdim + scol;
    const int ldsW = w * 8 * 64;                  // wave-uniform base offset
    const size_t rstep = (size_t)32 * Kdim;       // 32 global rows

#define STAGE_TILE(buf, koff) do {                                   \
        GLD(gA + (koff),             &As[buf][ldsW]);                \
        GLD(gA + (koff) + rstep,     &As[buf][ldsW + 32 * 64]);      \
        GLD(gA + (koff) + 2 * rstep, &As[buf][ldsW + 64 * 64]);      \
        GLD(gA + (koff) + 3 * rstep, &As[buf][ldsW + 96 * 64]);      \
        GLD(gB + (koff),             &Bs[buf][ldsW]);                \
        GLD(gB + (koff) + rstep,     &Bs[buf][ldsW + 32 * 64]);      \
        GLD(gB + (koff) + 2 * rstep, &Bs[buf][ldsW + 64 * 64]);      \
        GLD(gB + (koff) + 3 * rstep, &Bs[buf][ldsW + 96 * 64]);      \
        GLD(gB + (koff) + 4 * rstep, &Bs[buf][ldsW + 128 * 64]);     \
        GLD(gB + (koff) + 5 * rstep, &Bs[buf][ldsW + 160 * 64]);     \
        GLD(gB + (koff) + 6 * rstep, &Bs[buf][ldsW + 192 * 64]);     \
        GLD(gB + (koff) + 7 * rstep, &Bs[buf][ldsW + 224 * 64]);     \
    } while (0)

    // fragment reads: row = slab + idx*16 + l16, chunk slot = (kk*4+quad)^(row&7)
    const int swz = l16 & 7;       // == row&7 for all fragment rows
#define LDA_(base, i, kk) (*(const bf16x8*)&(base)[(wr * 64 + (i) * 16 + l16) * 64 + ((((kk) * 4 + quad) ^ swz) * 8)])
#define LDB_(base, j, kk) (*(const bf16x8*)&(base)[(wc * 128 + (j) * 16 + l16) * 64 + ((((kk) * 4 + quad) ^ swz) * 8)])

    const int nt = Kdim >> 6;      // K-tiles of 64 (nt >= 4 for K in {256, 4096})

    // prologue: stage tiles 0 and 1; wait tile 0 (12 newer outstanding), sync.
    STAGE_TILE(0, 0);
    STAGE_TILE(1, 64);
    asm volatile("s_waitcnt vmcnt(12)" ::: "memory");
    __builtin_amdgcn_s_barrier();

    for (int tt = 0; tt < nt; ++tt) {
        const int buf = tt % 3;
        const int nb = (tt + 2) % 3;
        const int koff = (tt + 2) << 6;
        const bool more = (tt + 2) < nt;

        const ushort_t* __restrict__ Ab = &As[buf][0];
        const ushort_t* __restrict__ Bb = &Bs[buf][0];

        // all fragment reads of this K-tile (fully unrolled -> static indices;
        // compiler schedules with counted lgkmcnt before dependent MFMAs)
        bf16x8 af[2][4], bfr[2][8];
#pragma unroll
        for (int kk = 0; kk < 2; ++kk) {
#pragma unroll
            for (int i = 0; i < 4; ++i) af[kk][i] = LDA_(Ab, i, kk);
#pragma unroll
            for (int j = 0; j < 8; ++j) bfr[kk][j] = LDB_(Bb, j, kk);
        }

        // stage tile tt+2 (vmcnt-counted; in flight ~2 tile-times)
        if (more) STAGE_TILE(nb, koff);

        // 64 MFMAs, single barrier-free region (per-acc order: kk0 then kk1)
#pragma unroll
        for (int kk = 0; kk < 2; ++kk)
#pragma unroll
            for (int i = 0; i < 4; ++i)
#pragma unroll
                for (int j = 0; j < 8; ++j)
                    MFMA(acc[i][j], af[kk][i], bfr[kk][j]);

        if (tt + 1 < nt) {
            // next iter reads buf (tt+1)%3: its 12 loads must be done. Newer in
            // flight = tile tt+2's 12 iff staged this iter -> vmcnt(12), else drain.
            if (more) asm volatile("s_waitcnt vmcnt(12)" ::: "memory");
            else      asm volatile("s_waitcnt vmcnt(0)" ::: "memory");
            __builtin_amdgcn_s_barrier();
        }
    }

    // epilogue: C/D layout col=lane&15, row=quad*4+reg (unchanged mapping)
#pragma unroll
    for (int i = 0; i < 4; ++i) {
#pragma unroll
        for (int r = 0; r < 4; ++r) {
            const int grow = m0 + wr * 64 + i * 16 + quad * 4 + r;
#pragma unroll
            for (int j = 0; j < 8; ++j) {
                const int gcol = n0 + wc * 128 + j * 16 + l16;
                float v = acc[i][j][r] + bias[gcol];
                if (RELU) v = fmaxf(v, 0.0f);
                if constexpr (sizeof(OutT) == 2) {
                    C[(size_t)grow * NDIM + gcol] = to_bf16(v);
                } else {
                    C[(size_t)grow * NDIM + gcol] = v;
                }
            }
        }
    }
}

// ---------------- Sinkhorn, factored: P = diag(a) K diag(b) ----------------
// (reverted to the round-3-proven readlane form; v2's LDS broadcast was +6us)
__device__ __forceinline__ float rdl(float v, int l) {
    return __uint_as_float(__builtin_amdgcn_readlane(__float_as_uint(v), l));
}

__global__ __launch_bounds__(64) void sinkhorn_kernel(float* __restrict__ PM) {
    __shared__ __align__(16) float T[64 * 65];  // one-time transpose staging
    const int l = threadIdx.x;
    float* base = PM + (size_t)blockIdx.x * 4096;

    float Kcol[64];  // Kcol[r] = K[r][l]  (column l)
    float Krow[64];  // Krow[c] = K[l][c]  (row l)
#pragma unroll
    for (int r = 0; r < 64; ++r)
        Kcol[r] = __expf(-base[r * 64 + l]);  // global /sum cancels in 1st row-norm
#pragma unroll
    for (int r = 0; r < 64; ++r)
        T[r * 65 + l] = Kcol[r];
    __syncthreads();
#pragma unroll
    for (int c = 0; c < 64; ++c)
        Krow[c] = T[l * 65 + c];  // stride-65: 2-way bank alias (free)

    float a = 0.0f, b = 1.0f;
    for (int it = 0; it < 1000; ++it) {
        float t1 = 0.0f;  // (K b)_row=l
#pragma unroll
        for (int c = 0; c < 64; ++c)
            t1 = fmaf(Krow[c], rdl(b, c), t1);
        a = 0.015625f / t1;  // r = 1/64

        float t2 = 0.0f;  // (K^T a)_col=l
#pragma unroll
        for (int r = 0; r < 64; ++r)
            t2 = fmaf(Kcol[r], rdl(a, r), t2);
        const float err = fabsf(b * t2 - 0.015625f);  // beta_c - c
        if (__ballot(err > 1e-6f) == 0ull) break;     // max over lanes <= eps
        b = 0.015625f / t2;
    }

    // writeback: P[r][l] = a_r * K[r][l] * b_l, coalesced per row
#pragma unroll
    for (int r = 0; r < 64; ++r)
        base[r * 64 + l] = rdl(a, r) * Kcol[r] * b;
}

extern "C" void kernel_launch(void* const* d_in, const int* in_sizes, int n_in,
                              void* d_out, int out_size, void* d_ws, size_t ws_size,
                              hipStream_t stream) {
    const float* z  = (const float*)d_in[0];
    const float* W1 = (const float*)d_in[1];
    const float* b1 = (const float*)d_in[2];
    const float* W2 = (const float*)d_in[3];
    const float* b2 = (const float*)d_in[4];
    const float* W3 = (const float*)d_in[5];
    const float* b3 = (const float*)d_in[6];
    float* out = (float*)d_out;
    char* ws = (char*)d_ws;

    // workspace layout (bytes)
    ushort_t* W2T = (ushort_t*)(ws + 0);                       // 4096*4096*2 = 32 MB
    ushort_t* W3T = (ushort_t*)(ws + (size_t)33554432);        // 32 MB
    ushort_t* C1b = (ushort_t*)(ws + (size_t)67108864);        // 2048*4096*2 = 16 MB
    ushort_t* C2b = (ushort_t*)(ws + (size_t)83886080);        // 16 MB
    ushort_t* Zb  = (ushort_t*)(ws + (size_t)100663296);       // 2048*256*2 = 1 MB
    ushort_t* W1T = (ushort_t*)(ws + (size_t)101711872);       // 4096*256*2 = 2 MB

    // prep
    cast_bf16_kernel<<<2048, 256, 0, stream>>>(z, Zb, MDIM * 256);
    transpose_cast_kernel<<<dim3(128, 8), dim3(32, 8), 0, stream>>>(W1, W1T, 256, 4096);
    transpose_cast_kernel<<<dim3(128, 128), dim3(32, 8), 0, stream>>>(W2, W2T, 4096, 4096);
    transpose_cast_kernel<<<dim3(128, 128), dim3(32, 8), 0, stream>>>(W3, W3T, 4096, 4096);

    // 3-layer MLP (bf16 MFMA, fp32 accum); layer 3 writes fp32 cost matrix into d_out
    gemm_p8<ushort_t, true><<<dim3(NDIM / 256, MDIM / 128), 256, 0, stream>>>(Zb, W1T, b1, C1b, 256);
    gemm_p8<ushort_t, true><<<dim3(NDIM / 256, MDIM / 128), 256, 0, stream>>>(C1b, W2T, b2, C2b, 4096);
    gemm_p8<float, false><<<dim3(NDIM / 256, MDIM / 128), 256, 0, stream>>>(C2b, W3T, b3, out, 4096);

    // Sinkhorn in-place on d_out (one wave per matrix, register-resident K)
    sinkhorn_kernel<<<2048, 64, 0, stream>>>(out);
}

// Round 9
// 333.749 us; speedup vs baseline: 1.0840x; 1.0840x over previous
//
#include <hip/hip_runtime.h>
#include <hip/hip_bf16.h>

typedef unsigned short ushort_t;
typedef __attribute__((ext_vector_type(8))) short bf16x8;   // 8 bf16 = 4 VGPRs
typedef __attribute__((ext_vector_type(4))) float f32x4;    // 4 fp32 acc

#define MDIM 2048
#define NDIM 4096

__device__ __forceinline__ ushort_t to_bf16(float f) {
    __hip_bfloat16 h = __float2bfloat16(f);
    return *reinterpret_cast<ushort_t*>(&h);
}

// ---------------- fused prep: cast z + transpose-cast W1,W2,W3 ----------------
// One dispatch instead of four (cuts 3 inter-dispatch graph gaps).
// Transpose tile: 32x32, float4 global loads (G13), ushort4 stores.
// Segments (blockIdx.x): [0,16384) W2 | [16384,32768) W3 | [32768,33792) W1 |
// [33792,34304) cast z.
__device__ __forceinline__ void transpose_tile32(const float* __restrict__ W,
                                                 ushort_t* __restrict__ WT,
                                                 int K, int N, int n0, int k0,
                                                 float (*tile)[33]) {
    const int t = threadIdx.x;      // 256
    const int kr = t >> 3;          // 0..31 : k row
    const int nc = (t & 7) * 4;     // 0..28 : n col group of 4
    const float4 v = *reinterpret_cast<const float4*>(&W[(size_t)(k0 + kr) * N + n0 + nc]);
    tile[kr][nc + 0] = v.x;
    tile[kr][nc + 1] = v.y;
    tile[kr][nc + 2] = v.z;
    tile[kr][nc + 3] = v.w;
    __syncthreads();
    const int nl = t >> 3;          // 0..31 : local n
    const int kc = (t & 7) * 4;     // 0..28 : k chunk of 4
    ushort4 o;
    o.x = to_bf16(tile[kc + 0][nl]);
    o.y = to_bf16(tile[kc + 1][nl]);
    o.z = to_bf16(tile[kc + 2][nl]);
    o.w = to_bf16(tile[kc + 3][nl]);
    *reinterpret_cast<ushort4*>(&WT[(size_t)(n0 + nl) * K + k0 + kc]) = o;
}

__global__ __launch_bounds__(256) void prep_kernel(const float* __restrict__ z, ushort_t* __restrict__ Zb,
                                                   const float* __restrict__ W1, ushort_t* __restrict__ W1T,
                                                   const float* __restrict__ W2, ushort_t* __restrict__ W2T,
                                                   const float* __restrict__ W3, ushort_t* __restrict__ W3T) {
    __shared__ float tile[32][33];
    const int bid = blockIdx.x;
    if (bid < 16384) {
        // W2: K=4096, N=4096; 128 x 128 tiles
        const int bx = bid & 127, by = bid >> 7;
        transpose_tile32(W2, W2T, 4096, 4096, bx * 32, by * 32, tile);
    } else if (bid < 32768) {
        const int lb = bid - 16384;
        const int bx = lb & 127, by = lb >> 7;
        transpose_tile32(W3, W3T, 4096, 4096, bx * 32, by * 32, tile);
    } else if (bid < 33792) {
        // W1: K=256, N=4096; 128 x 8 tiles
        const int lb = bid - 32768;
        const int bx = lb & 127, by = lb >> 7;
        transpose_tile32(W1, W1T, 256, 4096, bx * 32, by * 32, tile);
    } else {
        // cast z: 2048*256 = 524288 fp32 -> bf16; 512 blocks x 256 thr x 4 elems
        const int i = ((bid - 33792) * 256 + threadIdx.x) * 4;
        const float4 v = *reinterpret_cast<const float4*>(&z[i]);
        ushort4 o;
        o.x = to_bf16(v.x); o.y = to_bf16(v.y); o.z = to_bf16(v.z); o.w = to_bf16(v.w);
        *reinterpret_cast<ushort4*>(&Zb[i]) = o;
    }
}

// ---------------- GEMM v4 (validated twice at 74us): single region per K-tile ----------------
// C[M][N] = act(A[M][K] @ BT[N][K]^T + bias)
// BM=128, BN=256, BK=64, 8 waves (2Mx4N), wave tile 64x64. Grid 16x16 = 1/CU.
// History: v2 phase-split neutral; v3 2-phase 84; v4 single-region 74 (best);
// v5/v7 B-bypass-LDS regressed (latency); v6 2-blocks/CU regressed (in-phase
// lock); v8 lgkm-split neutral; v9 4-wave big tiles regressed (1 wave/SIMD, no
// TLP). v4 = the optimum of this structural family: A+B via global_load_lds,
// 3 buffers, chunk-XOR swizzle (0 bank conflicts), counted vmcnt(6) (never 0
// mid-loop), ONE barrier per K-tile, all 16 ds_read_b128 + 32 MFMA in a single
// barrier-free region (compiler emits counted lgkmcnt interleave).

#define GLD(gp, lp) __builtin_amdgcn_global_load_lds(                      \
        (const __attribute__((address_space(1))) void*)(gp),               \
        (__attribute__((address_space(3))) void*)(lp), 16, 0, 0)

#define MFMA(d, a, b) d = __builtin_amdgcn_mfma_f32_16x16x32_bf16(a, b, d, 0, 0, 0)

template <typename OutT, bool RELU>
__global__ __launch_bounds__(512, 2) void gemm_p8(const ushort_t* __restrict__ A,
                                                  const ushort_t* __restrict__ BT,
                                                  const float* __restrict__ bias,
                                                  OutT* __restrict__ C, int Kdim) {
    __shared__ __align__(16) ushort_t As[3][128 * 64];   // 48 KB
    __shared__ __align__(16) ushort_t Bs[3][256 * 64];   // 96 KB

    const int t = threadIdx.x;
    const int l = t & 63;
    const int w = t >> 6;          // wave 0..7
    const int l16 = l & 15;
    const int quad = l >> 4;
    const int wr = w >> 2;         // 0..1  (M)
    const int wc = w & 3;          // 0..3  (N)
    const int m0 = blockIdx.y * 128;
    const int n0 = blockIdx.x * 256;

    f32x4 acc[4][4];
#pragma unroll
    for (int i = 0; i < 4; ++i)
#pragma unroll
        for (int j = 0; j < 4; ++j) acc[i][j] = (f32x4){0.f, 0.f, 0.f, 0.f};

    // --- staging addressing (chunk-XOR swizzle, verified conflict-free) ---
    const int srow = w * 8 + (l >> 3);
    const int scol = ((l & 7) ^ (l >> 3)) * 8;   // swizzled 16B chunk within the K-tile
    const ushort_t* gA0 = A  + (size_t)(m0 + srow) * Kdim + scol;
    const ushort_t* gA1 = A  + (size_t)(m0 + 64 + srow) * Kdim + scol;
    const ushort_t* gB0 = BT + (size_t)(n0 + srow) * Kdim + scol;
    const ushort_t* gB1 = BT + (size_t)(n0 + 64 + srow) * Kdim + scol;
    const ushort_t* gB2 = BT + (size_t)(n0 + 128 + srow) * Kdim + scol;
    const ushort_t* gB3 = BT + (size_t)(n0 + 192 + srow) * Kdim + scol;
    const int ldsW = w * 8 * 64;   // wave-uniform element offset of this wave's 8 rows

    // fragment reads: row = (wtile + i*16 + l16), chunk slot = (kk*4+quad)^(row&7)
    const int swz = l16 & 7;       // == row&7 for all our fragment rows
#define LDA_(base, i, kk) (*(const bf16x8*)&(base)[(wr * 64 + (i) * 16 + l16) * 64 + ((((kk) * 4 + quad) ^ swz) * 8)])
#define LDB_(base, j, kk) (*(const bf16x8*)&(base)[(wc * 64 + (j) * 16 + l16) * 64 + ((((kk) * 4 + quad) ^ swz) * 8)])

#define STAGE_TILE(buf, koff) do {                      \
        GLD(gA0 + (koff), &As[buf][ldsW]);              \
        GLD(gA1 + (koff), &As[buf][ldsW + 64 * 64]);    \
        GLD(gB0 + (koff), &Bs[buf][ldsW]);              \
        GLD(gB1 + (koff), &Bs[buf][ldsW + 64 * 64]);    \
        GLD(gB2 + (koff), &Bs[buf][ldsW + 128 * 64]);   \
        GLD(gB3 + (koff), &Bs[buf][ldsW + 192 * 64]);   \
    } while (0)

    // 16 MFMAs at one kk (i-major, j-minor -> per-acc order identical to prior versions)
#define MFMA16(a0, a1, a2, a3, b0, b1, b2, b3)                     \
        MFMA(acc[0][0], a0, b0); MFMA(acc[0][1], a0, b1);          \
        MFMA(acc[0][2], a0, b2); MFMA(acc[0][3], a0, b3);          \
        MFMA(acc[1][0], a1, b0); MFMA(acc[1][1], a1, b1);          \
        MFMA(acc[1][2], a1, b2); MFMA(acc[1][3], a1, b3);          \
        MFMA(acc[2][0], a2, b0); MFMA(acc[2][1], a2, b1);          \
        MFMA(acc[2][2], a2, b2); MFMA(acc[2][3], a2, b3);          \
        MFMA(acc[3][0], a3, b0); MFMA(acc[3][1], a3, b1);          \
        MFMA(acc[3][2], a3, b2); MFMA(acc[3][3], a3, b3)

    const int nt = Kdim >> 6;      // K-tiles of 64 (nt >= 2 for K in {256, 4096})

    // prologue: stage tiles 0 and 1; wait tile 0 (6 newer outstanding), sync.
    STAGE_TILE(0, 0);
    STAGE_TILE(1, 64);
    asm volatile("s_waitcnt vmcnt(6)" ::: "memory");
    __builtin_amdgcn_s_barrier();

    for (int tt = 0; tt < nt; ++tt) {
        const int buf = tt % 3;
        const int nb = (tt + 2) % 3;
        const int koff = (tt + 2) << 6;
        const bool more = (tt + 2) < nt;

        const ushort_t* __restrict__ Ab = &As[buf][0];
        const ushort_t* __restrict__ Bb = &Bs[buf][0];

        // all 16 fragment reads of this K-tile (compiler issues these and uses
        // counted lgkmcnt before the dependent MFMAs)
        bf16x8 a00 = LDA_(Ab, 0, 0), a01 = LDA_(Ab, 1, 0), a02 = LDA_(Ab, 2, 0), a03 = LDA_(Ab, 3, 0);
        bf16x8 b00 = LDB_(Bb, 0, 0), b01 = LDB_(Bb, 1, 0), b02 = LDB_(Bb, 2, 0), b03 = LDB_(Bb, 3, 0);
        bf16x8 a10 = LDA_(Ab, 0, 1), a11 = LDA_(Ab, 1, 1), a12 = LDA_(Ab, 2, 1), a13 = LDA_(Ab, 3, 1);
        bf16x8 b10 = LDB_(Bb, 0, 1), b11 = LDB_(Bb, 1, 1), b12 = LDB_(Bb, 2, 1), b13 = LDB_(Bb, 3, 1);

        // stage tile tt+2 (in flight for ~2 tile-times; waited via counted vmcnt)
        if (more) STAGE_TILE(nb, koff);

        // 32 MFMAs, single barrier-free region
        MFMA16(a00, a01, a02, a03, b00, b01, b02, b03);
        MFMA16(a10, a11, a12, a13, b10, b11, b12, b13);

        if (tt + 1 < nt) {
            // next iter reads buf (tt+1)%3: its 6 loads (all waves) must be done.
            // Own newer in flight = tile tt+2's 6 iff staged -> vmcnt(6), else drain.
            if (more) asm volatile("s_waitcnt vmcnt(6)" ::: "memory");
            else      asm volatile("s_waitcnt vmcnt(0)" ::: "memory");
            __builtin_amdgcn_s_barrier();
        }
    }

    // epilogue: C/D layout col=lane&15, row=quad*4+reg (unchanged mapping)
#pragma unroll
    for (int i = 0; i < 4; ++i) {
#pragma unroll
        for (int r = 0; r < 4; ++r) {
            const int grow = m0 + wr * 64 + i * 16 + quad * 4 + r;
#pragma unroll
            for (int j = 0; j < 4; ++j) {
                const int gcol = n0 + wc * 64 + j * 16 + l16;
                float v = acc[i][j][r] + bias[gcol];
                if (RELU) v = fmaxf(v, 0.0f);
                if constexpr (sizeof(OutT) == 2) {
                    C[(size_t)grow * NDIM + gcol] = to_bf16(v);
                } else {
                    C[(size_t)grow * NDIM + gcol] = v;
                }
            }
        }
    }
}

// ---------------- Sinkhorn, factored: P = diag(a) K diag(b) ----------------
// (round-3-proven readlane form; per-element cost is at the 2-inst floor:
// v_readlane -> SGPR feeding v_fmac directly)
__device__ __forceinline__ float rdl(float v, int l) {
    return __uint_as_float(__builtin_amdgcn_readlane(__float_as_uint(v), l));
}

__global__ __launch_bounds__(64) void sinkhorn_kernel(float* __restrict__ PM) {
    __shared__ __align__(16) float T[64 * 65];  // one-time transpose staging
    const int l = threadIdx.x;
    float* base = PM + (size_t)blockIdx.x * 4096;

    float Kcol[64];  // Kcol[r] = K[r][l]  (column l)
    float Krow[64];  // Krow[c] = K[l][c]  (row l)
#pragma unroll
    for (int r = 0; r < 64; ++r)
        Kcol[r] = __expf(-base[r * 64 + l]);  // global /sum cancels in 1st row-norm
#pragma unroll
    for (int r = 0; r < 64; ++r)
        T[r * 65 + l] = Kcol[r];
    __syncthreads();
#pragma unroll
    for (int c = 0; c < 64; ++c)
        Krow[c] = T[l * 65 + c];  // stride-65: 2-way bank alias (free)

    float a = 0.0f, b = 1.0f;
    for (int it = 0; it < 1000; ++it) {
        float t1 = 0.0f;  // (K b)_row=l
#pragma unroll
        for (int c = 0; c < 64; ++c)
            t1 = fmaf(Krow[c], rdl(b, c), t1);
        a = 0.015625f / t1;  // r = 1/64

        float t2 = 0.0f;  // (K^T a)_col=l
#pragma unroll
        for (int r = 0; r < 64; ++r)
            t2 = fmaf(Kcol[r], rdl(a, r), t2);
        const float err = fabsf(b * t2 - 0.015625f);  // beta_c - c
        if (__ballot(err > 1e-6f) == 0ull) break;     // max over lanes <= eps
        b = 0.015625f / t2;
    }

    // writeback: P[r][l] = a_r * K[r][l] * b_l, coalesced per row
#pragma unroll
    for (int r = 0; r < 64; ++r)
        base[r * 64 + l] = rdl(a, r) * Kcol[r] * b;
}

extern "C" void kernel_launch(void* const* d_in, const int* in_sizes, int n_in,
                              void* d_out, int out_size, void* d_ws, size_t ws_size,
                              hipStream_t stream) {
    const float* z  = (const float*)d_in[0];
    const float* W1 = (const float*)d_in[1];
    const float* b1 = (const float*)d_in[2];
    const float* W2 = (const float*)d_in[3];
    const float* b2 = (const float*)d_in[4];
    const float* W3 = (const float*)d_in[5];
    const float* b3 = (const float*)d_in[6];
    float* out = (float*)d_out;
    char* ws = (char*)d_ws;

    // workspace layout (bytes)
    ushort_t* W2T = (ushort_t*)(ws + 0);                       // 4096*4096*2 = 32 MB
    ushort_t* W3T = (ushort_t*)(ws + (size_t)33554432);        // 32 MB
    ushort_t* C1b = (ushort_t*)(ws + (size_t)67108864);        // 2048*4096*2 = 16 MB
    ushort_t* C2b = (ushort_t*)(ws + (size_t)83886080);        // 16 MB
    ushort_t* Zb  = (ushort_t*)(ws + (size_t)100663296);       // 2048*256*2 = 1 MB
    ushort_t* W1T = (ushort_t*)(ws + (size_t)101711872);       // 4096*256*2 = 2 MB

    // fused prep: cast z + transpose-cast W1,W2,W3 (one dispatch)
    prep_kernel<<<34304, 256, 0, stream>>>(z, Zb, W1, W1T, W2, W2T, W3, W3T);

    // 3-layer MLP (bf16 MFMA, fp32 accum); layer 3 writes fp32 cost matrix into d_out
    gemm_p8<ushort_t, true><<<dim3(NDIM / 256, MDIM / 128), 512, 0, stream>>>(Zb, W1T, b1, C1b, 256);
    gemm_p8<ushort_t, true><<<dim3(NDIM / 256, MDIM / 128), 512, 0, stream>>>(C1b, W2T, b2, C2b, 4096);
    gemm_p8<float, false><<<dim3(NDIM / 256, MDIM / 128), 512, 0, stream>>>(C2b, W3T, b3, out, 4096);

    // Sinkhorn in-place on d_out (one wave per matrix, register-resident K)
    sinkhorn_kernel<<<2048, 64, 0, stream>>>(out);
}